// Round 2
// baseline (282.307 us; speedup 1.0000x reference)
//
#include <hip/hip_runtime.h>

typedef __attribute__((ext_vector_type(8))) short bf16x8;
typedef __attribute__((ext_vector_type(4))) float f32x4;
typedef unsigned short ushort_t;

// ---------------- bf16 helpers ----------------
__device__ __forceinline__ float bf2f(ushort_t u) {
    unsigned int x = ((unsigned int)u) << 16;
    return __builtin_bit_cast(float, x);
}
__device__ __forceinline__ ushort_t f2bf(float f) {
    unsigned int x = __builtin_bit_cast(unsigned int, f);
    x += 0x7fffu + ((x >> 16) & 1u);   // round-to-nearest-even
    return (ushort_t)(x >> 16);
}

// ---------------- workspace layout (elements of ushort) ----------------
// Wt (Wq^T,Wq2^T,Wk^T,Wv^T) : 4 x [256][512] bf16 @ 0
// Wo^T                      : [512][256] bf16     @ 524288
// Q, Q2, K, V               : 4 x [8192][256] bf16 @ 655360 (+2097152 each)
// O                         : [8192][256] bf16     @ 9043968
#define WT_OFF   0
#define WOT_OFF  524288
#define QKV_OFF  655360
#define QKV_SZ   2097152
#define O_OFF    9043968

// ---------------- weight transpose + fp32->bf16 convert ----------------
__global__ __launch_bounds__(256) void transpose_w(
    const float* __restrict__ Wq, const float* __restrict__ Wq2,
    const float* __restrict__ Wk, const float* __restrict__ Wv,
    const float* __restrict__ Wo, ushort_t* __restrict__ ws)
{
    const int j = blockIdx.y;
    const int t = blockIdx.x * 256 + threadIdx.x;   // 0..131071
    const float* in;
    ushort_t* out;
    int C;
    if (j < 4) {
        in = (j == 0) ? Wq : (j == 1) ? Wq2 : (j == 2) ? Wk : Wv;
        out = ws + WT_OFF + (size_t)j * 131072;
        C = 256;                                    // in [512][256] -> out [256][512]
    } else {
        in = Wo; out = ws + WOT_OFF; C = 512;       // in [256][512] -> out [512][256]
    }
    const int R = 131072 / C;
    const int r = t / C, c = t % C;
    out[(size_t)c * R + r] = f2bf(in[t]);
}

// ---------------- generic 64x64-tile GEMM, B given transposed bf16 ([N][K]) ----------------
// A_F32: A operand is fp32 (converted to bf16 while staging). C_F32: output fp32.
template<bool A_F32, bool C_F32>
__device__ __forceinline__ void gemm_tile(
    const void* __restrict__ Ap, const ushort_t* __restrict__ Bt,
    void* __restrict__ Cp, const float* __restrict__ bias,
    int N, int K, float oscale, ushort_t* lA, ushort_t* lB)
{
    const int tid = threadIdx.x;
    const int wave = tid >> 6, lane = tid & 63;
    const int quad = lane >> 4, l16 = lane & 15;
    const size_t row0 = (size_t)blockIdx.x * 64;
    const int col0 = blockIdx.y * 64;

    f32x4 acc[4] = {};

    const int sr = tid >> 2;            // 0..63
    const int sc = (tid & 3) << 3;      // 0,8,16,24

    for (int k0 = 0; k0 < K; k0 += 32) {
        if (A_F32) {
            const float* A = (const float*)Ap;
            const float* src = A + (row0 + sr) * (size_t)K + k0 + sc;
            float4 v0 = *(const float4*)(src);
            float4 v1 = *(const float4*)(src + 4);
            ushort_t tmp[8] = { f2bf(v0.x), f2bf(v0.y), f2bf(v0.z), f2bf(v0.w),
                                f2bf(v1.x), f2bf(v1.y), f2bf(v1.z), f2bf(v1.w) };
            *(uint4*)&lA[sr * 40 + sc] = *(const uint4*)tmp;
        } else {
            const ushort_t* A = (const ushort_t*)Ap;
            *(uint4*)&lA[sr * 40 + sc] = *(const uint4*)(A + (row0 + sr) * (size_t)K + k0 + sc);
        }
        *(uint4*)&lB[sr * 40 + sc] = *(const uint4*)(Bt + (size_t)(col0 + sr) * K + k0 + sc);
        __syncthreads();
        bf16x8 af = *(const bf16x8*)&lA[(wave * 16 + l16) * 40 + quad * 8];
#pragma unroll
        for (int c = 0; c < 4; ++c) {
            bf16x8 bfr = *(const bf16x8*)&lB[(c * 16 + l16) * 40 + quad * 8];
            acc[c] = __builtin_amdgcn_mfma_f32_16x16x32_bf16(af, bfr, acc[c], 0, 0, 0);
        }
        __syncthreads();
    }
#pragma unroll
    for (int c = 0; c < 4; ++c) {
        const int col = col0 + c * 16 + l16;
        const float bv = bias ? bias[col] : 0.f;
#pragma unroll
        for (int r = 0; r < 4; ++r) {
            const size_t row = row0 + wave * 16 + quad * 4 + r;
            const float val = acc[c][r] * oscale + bv;
            if (C_F32) ((float*)Cp)[row * N + col] = val;
            else       ((ushort_t*)Cp)[row * N + col] = f2bf(val);
        }
    }
}

// jobs z: 0: Q = x1@Wq * 0.125 ; 1: Q2 = x2@Wq2 * 0.125 ; 2: K = ctx@Wk ; 3: V = ctx@Wv
__global__ __launch_bounds__(256) void proj_gemm(
    const float* __restrict__ x1, const float* __restrict__ x2,
    const float* __restrict__ ctx, const ushort_t* __restrict__ Wt,
    ushort_t* __restrict__ QKV)
{
    __shared__ __align__(16) ushort_t lA[64 * 40];
    __shared__ __align__(16) ushort_t lB[64 * 40];
    const int z = blockIdx.z;
    const float* A = (z == 0) ? x1 : (z == 1) ? x2 : ctx;
    const ushort_t* Bt = Wt + (size_t)z * 131072;
    ushort_t* C = QKV + (size_t)z * QKV_SZ;
    const float sc = (z < 2) ? 0.125f : 1.0f;   // fold attention SCALE into Q, Q2
    gemm_tile<true, false>(A, Bt, C, nullptr, 256, 512, sc, lA, lB);
}

__global__ __launch_bounds__(256) void out_gemm(
    const ushort_t* __restrict__ O, const ushort_t* __restrict__ Wot,
    const float* __restrict__ bias, float* __restrict__ out)
{
    __shared__ __align__(16) ushort_t lA[64 * 40];
    __shared__ __align__(16) ushort_t lB[64 * 40];
    gemm_tile<false, true>(O, Wot, out, bias, 512, 256, 1.0f, lA, lB);
}

// ---------------- fused dual-softmax flash attention ----------------
// grid: (32 q-tiles, 16 bh). Q/Q2/K/V layout: [8192 tokens][256 inner=h*64+d], bf16.
__global__ __launch_bounds__(256) void attn_fused(
    const ushort_t* __restrict__ Qb, const ushort_t* __restrict__ Q2b,
    const ushort_t* __restrict__ Kb, const ushort_t* __restrict__ Vb,
    ushort_t* __restrict__ Ob)
{
    __shared__ __align__(16) ushort_t lK[64 * 72];       // K tile [m][d], pad->72
    __shared__ __align__(16) ushort_t lV[64 * 72];       // V^T tile [d][m]
    __shared__ __align__(16) ushort_t lP1[4][16 * 72];   // per-wave P tiles
    __shared__ __align__(16) ushort_t lP2[4][16 * 72];

    const int qt = blockIdx.x;          // 0..31
    const int bh = blockIdx.y;          // 0..15
    const int bb = bh >> 2, hh = bh & 3;
    const int tid = threadIdx.x;
    const int wave = tid >> 6, lane = tid & 63;
    const int quad = lane >> 4, l16 = lane & 15;
    const size_t tok0 = (size_t)bb * 2048;
    const int in0 = hh * 64;

    // ---- load Q / Q2 fragments (scale already folded in) ----
    bf16x8 q1f[2], q2f[2];
#pragma unroll
    for (int it = 0; it < 2; ++it) {
        const int cc = tid + it * 256;
        const int r = cc >> 3, c8 = (cc & 7) << 3;
        uint4 v = *(const uint4*)(Qb + (tok0 + qt * 64 + r) * 256 + in0 + c8);
        *(uint4*)&lK[r * 72 + c8] = v;
    }
    __syncthreads();
    q1f[0] = *(const bf16x8*)&lK[(wave * 16 + l16) * 72 + quad * 8];
    q1f[1] = *(const bf16x8*)&lK[(wave * 16 + l16) * 72 + 32 + quad * 8];
    __syncthreads();
#pragma unroll
    for (int it = 0; it < 2; ++it) {
        const int cc = tid + it * 256;
        const int r = cc >> 3, c8 = (cc & 7) << 3;
        uint4 v = *(const uint4*)(Q2b + (tok0 + qt * 64 + r) * 256 + in0 + c8);
        *(uint4*)&lK[r * 72 + c8] = v;
    }
    __syncthreads();
    q2f[0] = *(const bf16x8*)&lK[(wave * 16 + l16) * 72 + quad * 8];
    q2f[1] = *(const bf16x8*)&lK[(wave * 16 + l16) * 72 + 32 + quad * 8];
    __syncthreads();

    f32x4 o1[4] = {}, o2[4] = {};
    float m1[4], l1[4], m2[4], l2[4];
#pragma unroll
    for (int r = 0; r < 4; ++r) { m1[r] = -1e30f; m2[r] = -1e30f; l1[r] = 0.f; l2[r] = 0.f; }

    for (int m0 = 0; m0 < 2048; m0 += 64) {
        // stage K tile and transposed V tile
#pragma unroll
        for (int it = 0; it < 2; ++it) {
            const int cc = tid + it * 256;
            const int r = cc >> 3, c8 = (cc & 7) << 3;
            uint4 kv = *(const uint4*)(Kb + (tok0 + m0 + r) * 256 + in0 + c8);
            *(uint4*)&lK[r * 72 + c8] = kv;
            uint4 vv = *(const uint4*)(Vb + (tok0 + m0 + r) * 256 + in0 + c8);
            const ushort_t* ve = (const ushort_t*)&vv;
#pragma unroll
            for (int j = 0; j < 8; ++j) lV[(c8 + j) * 72 + r] = ve[j];
        }
        __syncthreads();

        // S1 = Q K^T, S2 = Q2 K^T (scale pre-folded)
        f32x4 s1[4] = {}, s2[4] = {};
#pragma unroll
        for (int c = 0; c < 4; ++c) {
#pragma unroll
            for (int ks = 0; ks < 2; ++ks) {
                bf16x8 kf = *(const bf16x8*)&lK[(c * 16 + l16) * 72 + ks * 32 + quad * 8];
                s1[c] = __builtin_amdgcn_mfma_f32_16x16x32_bf16(q1f[ks], kf, s1[c], 0, 0, 0);
                s2[c] = __builtin_amdgcn_mfma_f32_16x16x32_bf16(q2f[ks], kf, s2[c], 0, 0, 0);
            }
        }

        // online softmax update for both attention maps
        float a1[4], a2[4];
#pragma unroll
        for (int r = 0; r < 4; ++r) {
            float mx1 = -1e30f, mx2 = -1e30f;
#pragma unroll
            for (int c = 0; c < 4; ++c) {
                mx1 = fmaxf(mx1, s1[c][r]);
                mx2 = fmaxf(mx2, s2[c][r]);
            }
#pragma unroll
            for (int d = 1; d < 16; d <<= 1) {
                mx1 = fmaxf(mx1, __shfl_xor(mx1, d, 64));
                mx2 = fmaxf(mx2, __shfl_xor(mx2, d, 64));
            }
            const float mn1 = fmaxf(m1[r], mx1), mn2 = fmaxf(m2[r], mx2);
            a1[r] = __expf(m1[r] - mn1);
            a2[r] = __expf(m2[r] - mn2);
            m1[r] = mn1; m2[r] = mn2;
            float ps1 = 0.f, ps2 = 0.f;
#pragma unroll
            for (int c = 0; c < 4; ++c) {
                const float p1 = __expf(s1[c][r] - mn1);
                const float p2 = __expf(s2[c][r] - mn2);
                lP1[wave][(quad * 4 + r) * 72 + c * 16 + l16] = f2bf(p1);
                lP2[wave][(quad * 4 + r) * 72 + c * 16 + l16] = f2bf(p2);
                ps1 += p1; ps2 += p2;
            }
#pragma unroll
            for (int d = 1; d < 16; d <<= 1) {
                ps1 += __shfl_xor(ps1, d, 64);
                ps2 += __shfl_xor(ps2, d, 64);
            }
            l1[r] = l1[r] * a1[r] + ps1;
            l2[r] = l2[r] * a2[r] + ps2;
        }
        __syncthreads();

        // rescale accumulators
#pragma unroll
        for (int c = 0; c < 4; ++c)
#pragma unroll
            for (int r = 0; r < 4; ++r) { o1[c][r] *= a1[r]; o2[c][r] *= a2[r]; }

        // O += P @ V
        bf16x8 p1f[2], p2f[2];
#pragma unroll
        for (int ks = 0; ks < 2; ++ks) {
            p1f[ks] = *(const bf16x8*)&lP1[wave][l16 * 72 + ks * 32 + quad * 8];
            p2f[ks] = *(const bf16x8*)&lP2[wave][l16 * 72 + ks * 32 + quad * 8];
        }
#pragma unroll
        for (int c = 0; c < 4; ++c) {
#pragma unroll
            for (int ks = 0; ks < 2; ++ks) {
                bf16x8 vf = *(const bf16x8*)&lV[(c * 16 + l16) * 72 + ks * 32 + quad * 8];
                o1[c] = __builtin_amdgcn_mfma_f32_16x16x32_bf16(p1f[ks], vf, o1[c], 0, 0, 0);
                o2[c] = __builtin_amdgcn_mfma_f32_16x16x32_bf16(p2f[ks], vf, o2[c], 0, 0, 0);
            }
        }
        __syncthreads();   // before next iteration overwrites lK/lV
    }

    // epilogue: out = 0.3*O1/l1 + 0.7*O2/l2
#pragma unroll
    for (int r = 0; r < 4; ++r) {
        const float i1 = 0.3f / l1[r], i2 = 0.7f / l2[r];
        const size_t row = tok0 + qt * 64 + wave * 16 + quad * 4 + r;
#pragma unroll
        for (int c = 0; c < 4; ++c) {
            Ob[row * 256 + in0 + c * 16 + l16] = f2bf(o1[c][r] * i1 + o2[c][r] * i2);
        }
    }
}

// ---------------- launch ----------------
extern "C" void kernel_launch(void* const* d_in, const int* in_sizes, int n_in,
                              void* d_out, int out_size, void* d_ws, size_t ws_size,
                              hipStream_t stream)
{
    (void)in_sizes; (void)n_in; (void)out_size; (void)ws_size;
    const float* x1  = (const float*)d_in[0];
    const float* x2  = (const float*)d_in[1];
    const float* ctx = (const float*)d_in[2];
    const float* Wq  = (const float*)d_in[3];
    const float* Wq2 = (const float*)d_in[4];
    const float* Wk  = (const float*)d_in[5];
    const float* Wv  = (const float*)d_in[6];
    const float* Wo  = (const float*)d_in[7];
    const float* bo  = (const float*)d_in[8];
    ushort_t* ws  = (ushort_t*)d_ws;
    float* out = (float*)d_out;

    ushort_t* Wt  = ws + WT_OFF;
    ushort_t* Wot = ws + WOT_OFF;
    ushort_t* QKV = ws + QKV_OFF;
    ushort_t* Q   = QKV;
    ushort_t* Q2  = QKV + 1 * (size_t)QKV_SZ;
    ushort_t* Kp  = QKV + 2 * (size_t)QKV_SZ;
    ushort_t* Vp  = QKV + 3 * (size_t)QKV_SZ;
    ushort_t* Op  = ws + O_OFF;

    transpose_w<<<dim3(512, 5), 256, 0, stream>>>(Wq, Wq2, Wk, Wv, Wo, ws);
    proj_gemm  <<<dim3(128, 4, 4), 256, 0, stream>>>(x1, x2, ctx, Wt, QKV);
    attn_fused <<<dim3(32, 16), 256, 0, stream>>>(Q, Q2, Kp, Vp, Op);
    out_gemm   <<<dim3(128, 8), 256, 0, stream>>>(Op, Wot, bo, out);
}

// Round 3
// 221.868 us; speedup vs baseline: 1.2724x; 1.2724x over previous
//
#include <hip/hip_runtime.h>

typedef __attribute__((ext_vector_type(8))) short bf16x8;
typedef __attribute__((ext_vector_type(4))) float f32x4;
typedef unsigned short ushort_t;
typedef unsigned int uint_t;

// ---------------- bf16 helpers ----------------
__device__ __forceinline__ float bf2f(ushort_t u) {
    unsigned int x = ((unsigned int)u) << 16;
    return __builtin_bit_cast(float, x);
}
__device__ __forceinline__ ushort_t f2bf(float f) {
    unsigned int x = __builtin_bit_cast(unsigned int, f);
    x += 0x7fffu + ((x >> 16) & 1u);   // round-to-nearest-even
    return (ushort_t)(x >> 16);
}
__device__ __forceinline__ uint_t pack2(float a, float b) {
    return (uint_t)f2bf(a) | ((uint_t)f2bf(b) << 16);
}

#define LOG2E 1.4426950408889634f

// ---------------- workspace layout (elements of ushort) ----------------
#define WT_OFF   0
#define WOT_OFF  524288
#define QKV_OFF  655360
#define QKV_SZ   2097152
#define O_OFF    9043968

// ---------------- weight transpose + fp32->bf16 convert ----------------
__global__ __launch_bounds__(256) void transpose_w(
    const float* __restrict__ Wq, const float* __restrict__ Wq2,
    const float* __restrict__ Wk, const float* __restrict__ Wv,
    const float* __restrict__ Wo, ushort_t* __restrict__ ws)
{
    const int j = blockIdx.y;
    const int t = blockIdx.x * 256 + threadIdx.x;
    const float* in;
    ushort_t* out;
    int C;
    if (j < 4) {
        in = (j == 0) ? Wq : (j == 1) ? Wq2 : (j == 2) ? Wk : Wv;
        out = ws + WT_OFF + (size_t)j * 131072;
        C = 256;
    } else {
        in = Wo; out = ws + WOT_OFF; C = 512;
    }
    const int R = 131072 / C;
    const int r = t / C, c = t % C;
    out[(size_t)c * R + r] = f2bf(in[t]);
}

// ---------------- generic 64x64-tile GEMM, B transposed bf16 ([N][K]) ----------------
template<bool A_F32, bool C_F32>
__device__ __forceinline__ void gemm_tile(
    const void* __restrict__ Ap, const ushort_t* __restrict__ Bt,
    void* __restrict__ Cp, const float* __restrict__ bias,
    int N, int K, float oscale, ushort_t* lA, ushort_t* lB)
{
    const int tid = threadIdx.x;
    const int wave = tid >> 6, lane = tid & 63;
    const int quad = lane >> 4, l16 = lane & 15;
    const size_t row0 = (size_t)blockIdx.x * 64;
    const int col0 = blockIdx.y * 64;

    f32x4 acc[4] = {};
    const int sr = tid >> 2;
    const int sc = (tid & 3) << 3;

    for (int k0 = 0; k0 < K; k0 += 32) {
        if (A_F32) {
            const float* A = (const float*)Ap;
            const float* src = A + (row0 + sr) * (size_t)K + k0 + sc;
            float4 v0 = *(const float4*)(src);
            float4 v1 = *(const float4*)(src + 4);
            ushort_t tmp[8] = { f2bf(v0.x), f2bf(v0.y), f2bf(v0.z), f2bf(v0.w),
                                f2bf(v1.x), f2bf(v1.y), f2bf(v1.z), f2bf(v1.w) };
            *(uint4*)&lA[sr * 40 + sc] = *(const uint4*)tmp;
        } else {
            const ushort_t* A = (const ushort_t*)Ap;
            *(uint4*)&lA[sr * 40 + sc] = *(const uint4*)(A + (row0 + sr) * (size_t)K + k0 + sc);
        }
        *(uint4*)&lB[sr * 40 + sc] = *(const uint4*)(Bt + (size_t)(col0 + sr) * K + k0 + sc);
        __syncthreads();
        bf16x8 af = *(const bf16x8*)&lA[(wave * 16 + l16) * 40 + quad * 8];
#pragma unroll
        for (int c = 0; c < 4; ++c) {
            bf16x8 bfr = *(const bf16x8*)&lB[(c * 16 + l16) * 40 + quad * 8];
            acc[c] = __builtin_amdgcn_mfma_f32_16x16x32_bf16(af, bfr, acc[c], 0, 0, 0);
        }
        __syncthreads();
    }
#pragma unroll
    for (int c = 0; c < 4; ++c) {
        const int col = col0 + c * 16 + l16;
        const float bv = bias ? bias[col] : 0.f;
#pragma unroll
        for (int r = 0; r < 4; ++r) {
            const size_t row = row0 + wave * 16 + quad * 4 + r;
            const float val = acc[c][r] * oscale + bv;
            if (C_F32) ((float*)Cp)[row * N + col] = val;
            else       ((ushort_t*)Cp)[row * N + col] = f2bf(val);
        }
    }
}

__global__ __launch_bounds__(256) void proj_gemm(
    const float* __restrict__ x1, const float* __restrict__ x2,
    const float* __restrict__ ctx, const ushort_t* __restrict__ Wt,
    ushort_t* __restrict__ QKV)
{
    __shared__ __align__(16) ushort_t lA[64 * 40];
    __shared__ __align__(16) ushort_t lB[64 * 40];
    const int z = blockIdx.z;
    const float* A = (z == 0) ? x1 : (z == 1) ? x2 : ctx;
    const ushort_t* Bt = Wt + (size_t)z * 131072;
    ushort_t* C = QKV + (size_t)z * QKV_SZ;
    // fold attention scale AND log2(e) into Q/Q2 so softmax can use exp2
    const float sc = (z < 2) ? (0.125f * LOG2E) : 1.0f;
    gemm_tile<true, false>(A, Bt, C, nullptr, 256, 512, sc, lA, lB);
}

__global__ __launch_bounds__(256) void out_gemm(
    const ushort_t* __restrict__ O, const ushort_t* __restrict__ Wot,
    const float* __restrict__ bias, float* __restrict__ out)
{
    __shared__ __align__(16) ushort_t lA[64 * 40];
    __shared__ __align__(16) ushort_t lB[64 * 40];
    gemm_tile<false, true>(O, Wot, out, bias, 512, 256, 1.0f, lA, lB);
}

// ---------------- fused dual-softmax flash attention (S^T orientation) ----------------
// K/Q LDS layout: row-major [row][64], 16B groups XOR-swizzled: group' = g ^ (row&7)
// V^T LDS layout: [d][64 tok], group' = (tok>>3) ^ vswz(d>>3)
__device__ __forceinline__ int vswz(int a) { return ((a & 1) << 2) | (a >> 1); }

__global__ __launch_bounds__(256) void attn_fused(
    const ushort_t* __restrict__ Qb, const ushort_t* __restrict__ Q2b,
    const ushort_t* __restrict__ Kb, const ushort_t* __restrict__ Vb,
    ushort_t* __restrict__ Ob)
{
    __shared__ __align__(16) ushort_t lK[2][64 * 64];
    __shared__ __align__(16) ushort_t lV[2][64 * 64];
    __shared__ __align__(16) ushort_t lP[4][2][16 * 72];

    const int qt = blockIdx.x;
    const int bh = blockIdx.y;
    const int bb = bh >> 2, hh = bh & 3;
    const int tid = threadIdx.x;
    const int wave = tid >> 6, lane = tid & 63;
    const int quad = lane >> 4, l16 = lane & 15;
    const size_t tok0 = (size_t)bb * 2048;
    const int in0 = hh * 64;

    // ---- stage Q1/Q2 (swizzled) and read B-operand fragments ----
    bf16x8 q1f[2], q2f[2];
    {
        const int cc = tid;   // 256 threads x 2 iters
#pragma unroll
        for (int it = 0; it < 2; ++it) {
            const int c2 = cc + it * 256;
            const int g = ((c2 ^ (c2 >> 3)) & 7);
            *(uint4*)&lK[0][c2 * 8] =
                *(const uint4*)(Qb + (tok0 + qt * 64 + (c2 >> 3)) * 256 + in0 + g * 8);
        }
        __syncthreads();
#pragma unroll
        for (int ks = 0; ks < 2; ++ks)
            q1f[ks] = *(const bf16x8*)&lK[0][(wave * 16 + l16) * 64 +
                                            ((((ks * 4 + quad) ^ (l16 & 7)) & 7) << 3)];
        __syncthreads();
#pragma unroll
        for (int it = 0; it < 2; ++it) {
            const int c2 = cc + it * 256;
            const int g = ((c2 ^ (c2 >> 3)) & 7);
            *(uint4*)&lK[0][c2 * 8] =
                *(const uint4*)(Q2b + (tok0 + qt * 64 + (c2 >> 3)) * 256 + in0 + g * 8);
        }
        __syncthreads();
#pragma unroll
        for (int ks = 0; ks < 2; ++ks)
            q2f[ks] = *(const bf16x8*)&lK[0][(wave * 16 + l16) * 64 +
                                            ((((ks * 4 + quad) ^ (l16 & 7)) & 7) << 3)];
        __syncthreads();
    }

    // ---- prefetch tile 0 ----
    uint4 vr0, vr1;
    {
#pragma unroll
        for (int it = 0; it < 2; ++it) {
            const int cc = tid + it * 256;
            uint4 v = *(const uint4*)(Vb + (tok0 + 0 + (cc >> 3)) * 256 + in0 + (cc & 7) * 8);
            if (it == 0) vr0 = v; else vr1 = v;
        }
#pragma unroll
        for (int it = 0; it < 2; ++it) {
            const int cc = tid + it * 256;
            const int g = ((cc ^ (cc >> 3)) & 7);
            const ushort_t* gp = Kb + (tok0 + 0 + (cc >> 3)) * 256 + in0 + g * 8;
            __builtin_amdgcn_global_load_lds(
                (const __attribute__((address_space(1))) void*)gp,
                (__attribute__((address_space(3))) void*)&lK[0][cc * 8], 16, 0, 0);
        }
        // V^T(0) -> lV[0] (published by first loop barrier)
#pragma unroll
        for (int it = 0; it < 2; ++it) {
            const int cc = tid + it * 256;
            const uint4 v = (it == 0) ? vr0 : vr1;
            const ushort_t* ve = (const ushort_t*)&v;
            const int a = cc & 7;
            const int base = ((cc >> 6) ^ vswz(a)) & 7;
#pragma unroll
            for (int j = 0; j < 8; ++j)
                lV[0][(a * 8 + j) * 64 + base * 8 + ((cc >> 3) & 7)] = ve[j];
        }
    }

    f32x4 o1[4] = {}, o2[4] = {};
    float m1 = -1e30f, m2 = -1e30f, l1 = 0.f, l2 = 0.f;   // per qrow = l16 (replicated x4 quads)

    for (int i = 0; i < 32; ++i) {
        const int p = i & 1;
        const int m0n = (i + 1) * 64;

        __syncthreads();   // publishes lK[p], lV[p]; all waves done with buf 1-p

        // prefetch tile i+1 (V first so its vmcnt-wait doesn't drain K's loads)
        if (m0n < 2048) {
#pragma unroll
            for (int it = 0; it < 2; ++it) {
                const int cc = tid + it * 256;
                uint4 v = *(const uint4*)(Vb + (tok0 + m0n + (cc >> 3)) * 256 + in0 + (cc & 7) * 8);
                if (it == 0) vr0 = v; else vr1 = v;
            }
#pragma unroll
            for (int it = 0; it < 2; ++it) {
                const int cc = tid + it * 256;
                const int g = ((cc ^ (cc >> 3)) & 7);
                const ushort_t* gp = Kb + (tok0 + m0n + (cc >> 3)) * 256 + in0 + g * 8;
                __builtin_amdgcn_global_load_lds(
                    (const __attribute__((address_space(1))) void*)gp,
                    (__attribute__((address_space(3))) void*)&lK[1 - p][cc * 8], 16, 0, 0);
            }
        }

        // ---- S^T = K Q^T : A = K-frag (m=ktok), B = Q-frag (n=qrow) ----
        f32x4 st1[4] = {}, st2[4] = {};
#pragma unroll
        for (int c = 0; c < 4; ++c) {
#pragma unroll
            for (int ks = 0; ks < 2; ++ks) {
                bf16x8 kf = *(const bf16x8*)&lK[p][(c * 16 + l16) * 64 +
                                                  ((((ks * 4 + quad) ^ (l16 & 7)) & 7) << 3)];
                st1[c] = __builtin_amdgcn_mfma_f32_16x16x32_bf16(kf, q1f[ks], st1[c], 0, 0, 0);
                st2[c] = __builtin_amdgcn_mfma_f32_16x16x32_bf16(kf, q2f[ks], st2[c], 0, 0, 0);
            }
        }

        // ---- dual online softmax; rows are lanes (l16 = qrow) ----
        float mx1 = -1e30f, mx2 = -1e30f;
#pragma unroll
        for (int c = 0; c < 4; ++c)
#pragma unroll
            for (int r = 0; r < 4; ++r) {
                mx1 = fmaxf(mx1, st1[c][r]);
                mx2 = fmaxf(mx2, st2[c][r]);
            }
        mx1 = fmaxf(mx1, __shfl_xor(mx1, 16, 64));
        mx1 = fmaxf(mx1, __shfl_xor(mx1, 32, 64));
        mx2 = fmaxf(mx2, __shfl_xor(mx2, 16, 64));
        mx2 = fmaxf(mx2, __shfl_xor(mx2, 32, 64));
        const float mn1 = fmaxf(m1, mx1), mn2 = fmaxf(m2, mx2);
        const float al1 = __builtin_amdgcn_exp2f(m1 - mn1);
        const float al2 = __builtin_amdgcn_exp2f(m2 - mn2);
        m1 = mn1; m2 = mn2;

        float ps1 = 0.f, ps2 = 0.f;
        ushort_t* lPw0 = &lP[wave][0][0];
        ushort_t* lPw1 = &lP[wave][1][0];
#pragma unroll
        for (int c = 0; c < 4; ++c) {
            float p0 = __builtin_amdgcn_exp2f(st1[c][0] - mn1);
            float p1v = __builtin_amdgcn_exp2f(st1[c][1] - mn1);
            float p2v = __builtin_amdgcn_exp2f(st1[c][2] - mn1);
            float p3 = __builtin_amdgcn_exp2f(st1[c][3] - mn1);
            ps1 += (p0 + p1v) + (p2v + p3);
            uint2 w1; w1.x = pack2(p0, p1v); w1.y = pack2(p2v, p3);
            *(uint2*)&lPw0[l16 * 72 + c * 16 + quad * 4] = w1;
            float q0 = __builtin_amdgcn_exp2f(st2[c][0] - mn2);
            float q1v = __builtin_amdgcn_exp2f(st2[c][1] - mn2);
            float q2v = __builtin_amdgcn_exp2f(st2[c][2] - mn2);
            float q3 = __builtin_amdgcn_exp2f(st2[c][3] - mn2);
            ps2 += (q0 + q1v) + (q2v + q3);
            uint2 w2; w2.x = pack2(q0, q1v); w2.y = pack2(q2v, q3);
            *(uint2*)&lPw1[l16 * 72 + c * 16 + quad * 4] = w2;
        }
        ps1 += __shfl_xor(ps1, 16, 64); ps1 += __shfl_xor(ps1, 32, 64);
        ps2 += __shfl_xor(ps2, 16, 64); ps2 += __shfl_xor(ps2, 32, 64);
        l1 = l1 * al1 + ps1;
        l2 = l2 * al2 + ps2;

        // ---- broadcast alphas to accumulator rows (row = quad*4+r <-> lane l16=quad*4+r) ----
#pragma unroll
        for (int r = 0; r < 4; ++r) {
            const float a1b = __shfl(al1, quad * 20 + r, 64);
            const float a2b = __shfl(al2, quad * 20 + r, 64);
#pragma unroll
            for (int c = 0; c < 4; ++c) { o1[c][r] *= a1b; o2[c][r] *= a2b; }
        }

        // ---- write V^T(i+1) into lV[1-p] (overlaps: published by next barrier) ----
        if (m0n < 2048) {
#pragma unroll
            for (int it = 0; it < 2; ++it) {
                const int cc = tid + it * 256;
                const uint4 v = (it == 0) ? vr0 : vr1;
                const ushort_t* ve = (const ushort_t*)&v;
                const int a = cc & 7;
                const int base = ((cc >> 6) ^ vswz(a)) & 7;
#pragma unroll
                for (int j = 0; j < 8; ++j)
                    lV[1 - p][(a * 8 + j) * 64 + base * 8 + ((cc >> 3) & 7)] = ve[j];
            }
        }

        // ---- O += P @ V : A = P-frag, B = V-frag ----
        bf16x8 pa1[2], pa2[2];
#pragma unroll
        for (int ks = 0; ks < 2; ++ks) {
            pa1[ks] = *(const bf16x8*)&lPw0[l16 * 72 + ks * 32 + quad * 8];
            pa2[ks] = *(const bf16x8*)&lPw1[l16 * 72 + ks * 32 + quad * 8];
        }
#pragma unroll
        for (int c2 = 0; c2 < 4; ++c2) {
#pragma unroll
            for (int ks = 0; ks < 2; ++ks) {
                const int gs = ((ks * 4 + quad) ^ vswz((c2 * 2 + (l16 >> 3)) & 7)) & 7;
                bf16x8 vf = *(const bf16x8*)&lV[p][(c2 * 16 + l16) * 64 + (gs << 3)];
                o1[c2] = __builtin_amdgcn_mfma_f32_16x16x32_bf16(pa1[ks], vf, o1[c2], 0, 0, 0);
                o2[c2] = __builtin_amdgcn_mfma_f32_16x16x32_bf16(pa2[ks], vf, o2[c2], 0, 0, 0);
            }
        }
    }

    // ---- epilogue ----
    const float inv1 = 0.3f / l1, inv2 = 0.7f / l2;
#pragma unroll
    for (int r = 0; r < 4; ++r) {
        const float i1 = __shfl(inv1, quad * 20 + r, 64);
        const float i2 = __shfl(inv2, quad * 20 + r, 64);
        const size_t row = tok0 + qt * 64 + wave * 16 + quad * 4 + r;
#pragma unroll
        for (int c = 0; c < 4; ++c) {
            Ob[row * 256 + in0 + c * 16 + l16] = f2bf(o1[c][r] * i1 + o2[c][r] * i2);
        }
    }
}

// ---------------- launch ----------------
extern "C" void kernel_launch(void* const* d_in, const int* in_sizes, int n_in,
                              void* d_out, int out_size, void* d_ws, size_t ws_size,
                              hipStream_t stream)
{
    (void)in_sizes; (void)n_in; (void)out_size; (void)ws_size;
    const float* x1  = (const float*)d_in[0];
    const float* x2  = (const float*)d_in[1];
    const float* ctx = (const float*)d_in[2];
    const float* Wq  = (const float*)d_in[3];
    const float* Wq2 = (const float*)d_in[4];
    const float* Wk  = (const float*)d_in[5];
    const float* Wv  = (const float*)d_in[6];
    const float* Wo  = (const float*)d_in[7];
    const float* bo  = (const float*)d_in[8];
    ushort_t* ws  = (ushort_t*)d_ws;
    float* out = (float*)d_out;

    ushort_t* Wt  = ws + WT_OFF;
    ushort_t* Wot = ws + WOT_OFF;
    ushort_t* QKV = ws + QKV_OFF;
    ushort_t* Q   = QKV;
    ushort_t* Q2  = QKV + 1 * (size_t)QKV_SZ;
    ushort_t* Kp  = QKV + 2 * (size_t)QKV_SZ;
    ushort_t* Vp  = QKV + 3 * (size_t)QKV_SZ;
    ushort_t* Op  = ws + O_OFF;

    transpose_w<<<dim3(512, 5), 256, 0, stream>>>(Wq, Wq2, Wk, Wv, Wo, ws);
    proj_gemm  <<<dim3(128, 4, 4), 256, 0, stream>>>(x1, x2, ctx, Wt, QKV);
    attn_fused <<<dim3(32, 16), 256, 0, stream>>>(Q, Q2, Kp, Vp, Op);
    out_gemm   <<<dim3(128, 8), 256, 0, stream>>>(Op, Wot, bo, out);
}

// Round 5
// 194.935 us; speedup vs baseline: 1.4482x; 1.1382x over previous
//
#include <hip/hip_runtime.h>

typedef __attribute__((ext_vector_type(8))) short bf16x8;
typedef __attribute__((ext_vector_type(4))) float f32x4;
typedef unsigned short ushort_t;
typedef unsigned int uint_t;

__device__ __forceinline__ ushort_t f2bf(float f) {
    unsigned int x = __builtin_bit_cast(unsigned int, f);
    x += 0x7fffu + ((x >> 16) & 1u);   // RNE
    return (ushort_t)(x >> 16);
}
__device__ __forceinline__ uint_t pack2(float a, float b) {
    return (uint_t)f2bf(a) | ((uint_t)f2bf(b) << 16);
}

#define LOG2E 1.4426950408889634f

// ---------------- workspace layout (ushort elements) ----------------
// Wt (Wq^T,Wq2^T,Wk^T,Wv^T): 4 x [256][512] bf16 @ 0
// Wo^T: [512][256] bf16 @ 524288
// Q, Q2, K: [8192][256] bf16 ; V^T: [1024][2048] bf16  @ 655360 (+2097152 each)
// O: [8192][256] bf16 @ 9043968
#define WT_OFF   0
#define WOT_OFF  524288
#define QKV_OFF  655360
#define QKV_SZ   2097152
#define QKV_OFF_Z3 (3 * (size_t)QKV_SZ)
#define O_OFF    9043968

// ---------------- weight transpose + fp32->bf16 ----------------
__global__ __launch_bounds__(256) void transpose_w(
    const float* __restrict__ Wq, const float* __restrict__ Wq2,
    const float* __restrict__ Wk, const float* __restrict__ Wv,
    const float* __restrict__ Wo, ushort_t* __restrict__ ws)
{
    const int j = blockIdx.y;
    const int t = blockIdx.x * 256 + threadIdx.x;
    const float* in;
    ushort_t* out;
    int C;
    if (j < 4) {
        in = (j == 0) ? Wq : (j == 1) ? Wq2 : (j == 2) ? Wk : Wv;
        out = ws + WT_OFF + (size_t)j * 131072;
        C = 256;
    } else {
        in = Wo; out = ws + WOT_OFF; C = 512;
    }
    const int R = 131072 / C;
    const int r = t / C, c = t % C;
    out[(size_t)c * R + r] = f2bf(in[t]);
}

// ---------------- projections: 64x256 tile per block ----------------
// z: 0: Q=x1@Wq*s ; 1: Q2=x2@Wq2*s ; 2: K=ctx@Wk ; 3: V^T=(ctx@Wv)^T
__global__ __launch_bounds__(256) void proj_gemm(
    const float* __restrict__ x1, const float* __restrict__ x2,
    const float* __restrict__ ctx, const ushort_t* __restrict__ Wt,
    ushort_t* __restrict__ QKV)
{
    __shared__ __align__(16) ushort_t lA[64 * 40];
    __shared__ __align__(16) ushort_t lB[256 * 40];
    const int z = blockIdx.y;
    const float* A = (z == 0) ? x1 : (z == 1) ? x2 : ctx;
    const ushort_t* Bt = Wt + (size_t)z * 131072;
    const float sc = (z < 2) ? (0.125f * LOG2E) : 1.0f;
    const int tid = threadIdx.x;
    const int wave = tid >> 6, lane = tid & 63;
    const int quad = lane >> 4, l16 = lane & 15;
    const size_t row0 = (size_t)blockIdx.x * 64;
    const int sr = tid >> 2, sc8 = (tid & 3) << 3;

    f32x4 acc[16] = {};
    for (int k0 = 0; k0 < 512; k0 += 32) {
        const float* src = A + (row0 + sr) * 512 + k0 + sc8;
        float4 v0 = *(const float4*)src;
        float4 v1 = *(const float4*)(src + 4);
        ushort_t tmp[8] = { f2bf(v0.x), f2bf(v0.y), f2bf(v0.z), f2bf(v0.w),
                            f2bf(v1.x), f2bf(v1.y), f2bf(v1.z), f2bf(v1.w) };
        *(uint4*)&lA[sr * 40 + sc8] = *(const uint4*)tmp;
#pragma unroll
        for (int rr = 0; rr < 4; ++rr)
            *(uint4*)&lB[(rr * 64 + sr) * 40 + sc8] =
                *(const uint4*)(Bt + (size_t)(rr * 64 + sr) * 512 + k0 + sc8);
        __syncthreads();
        bf16x8 af = *(const bf16x8*)&lA[(wave * 16 + l16) * 40 + quad * 8];
#pragma unroll
        for (int c = 0; c < 16; ++c) {
            bf16x8 bfr = *(const bf16x8*)&lB[(c * 16 + l16) * 40 + quad * 8];
            acc[c] = __builtin_amdgcn_mfma_f32_16x16x32_bf16(af, bfr, acc[c], 0, 0, 0);
        }
        __syncthreads();
    }
    if (z == 3) {
        // V^T store: Vt[(b*4+h)*64 + d][tok]
        const int b = (int)(row0 >> 11);
        const int tokl = ((int)row0 & 2047) + wave * 16 + quad * 4;
        ushort_t* Vt = QKV + QKV_OFF_Z3;
#pragma unroll
        for (int c = 0; c < 16; ++c) {
            const int col = c * 16 + l16;
            const int h = col >> 6, d = col & 63;
            uint2 w;
            w.x = pack2(acc[c][0], acc[c][1]);
            w.y = pack2(acc[c][2], acc[c][3]);
            *(uint2*)(Vt + ((size_t)((b * 4 + h) * 64 + d)) * 2048 + tokl) = w;
        }
    } else {
        ushort_t* C = QKV + (size_t)z * QKV_SZ;
#pragma unroll
        for (int c = 0; c < 16; ++c) {
            const int col = c * 16 + l16;
#pragma unroll
            for (int r = 0; r < 4; ++r)
                C[(row0 + wave * 16 + quad * 4 + r) * 256 + col] = f2bf(acc[c][r] * sc);
        }
    }
}

// ---------------- output projection: 64x256 tile ----------------
__global__ __launch_bounds__(256) void out_gemm(
    const ushort_t* __restrict__ Op, const ushort_t* __restrict__ Wot,
    const float* __restrict__ bias, float* __restrict__ out)
{
    __shared__ __align__(16) ushort_t lA[64 * 40];
    __shared__ __align__(16) ushort_t lB[256 * 40];
    const int tid = threadIdx.x;
    const int wave = tid >> 6, lane = tid & 63;
    const int quad = lane >> 4, l16 = lane & 15;
    const size_t row0 = (size_t)blockIdx.x * 64;
    const int col0 = blockIdx.y * 256;
    const int sr = tid >> 2, sc8 = (tid & 3) << 3;

    f32x4 acc[16] = {};
    for (int k0 = 0; k0 < 256; k0 += 32) {
        *(uint4*)&lA[sr * 40 + sc8] = *(const uint4*)(Op + (row0 + sr) * 256 + k0 + sc8);
#pragma unroll
        for (int rr = 0; rr < 4; ++rr)
            *(uint4*)&lB[(rr * 64 + sr) * 40 + sc8] =
                *(const uint4*)(Wot + (size_t)(col0 + rr * 64 + sr) * 256 + k0 + sc8);
        __syncthreads();
        bf16x8 af = *(const bf16x8*)&lA[(wave * 16 + l16) * 40 + quad * 8];
#pragma unroll
        for (int c = 0; c < 16; ++c) {
            bf16x8 bfr = *(const bf16x8*)&lB[(c * 16 + l16) * 40 + quad * 8];
            acc[c] = __builtin_amdgcn_mfma_f32_16x16x32_bf16(af, bfr, acc[c], 0, 0, 0);
        }
        __syncthreads();
    }
#pragma unroll
    for (int c = 0; c < 16; ++c) {
        const int col = col0 + c * 16 + l16;
        const float bv = bias[col];
#pragma unroll
        for (int r = 0; r < 4; ++r)
            out[(row0 + wave * 16 + quad * 4 + r) * 512 + col] = acc[c][r] + bv;
    }
}

// ---------------- fused dual-softmax flash attention ----------------
// S^T = K·Q^T, static-max (p = exp2(s) raw), O^T = V^T·P^T.
// K LDS: [ktok][64 d], 16B-groups XOR-swizzled by ktok&7.
// V^T LDS: [d][64 tok], groups XOR-swizzled by d&7 (same formula).

#define ATTN_STAGE(MB, BUF) do {                                                        \
    _Pragma("unroll")                                                                   \
    for (int it_ = 0; it_ < 2; ++it_) {                                                 \
        const int cc_ = tid + it_ * 256;                                                \
        const int g_ = (cc_ ^ (cc_ >> 3)) & 7;                                          \
        const ushort_t* kp_ = Kb + (size_t)(tok0 + (MB) + (cc_ >> 3)) * 256 + in0 + g_ * 8; \
        __builtin_amdgcn_global_load_lds(                                               \
            (const __attribute__((address_space(1))) void*)kp_,                         \
            (__attribute__((address_space(3))) void*)&lK[BUF][cc_ * 8], 16, 0, 0);      \
        const ushort_t* vp_ = Vt + (size_t)(bh64 + (cc_ >> 3)) * 2048 + (MB) + g_ * 8;  \
        __builtin_amdgcn_global_load_lds(                                               \
            (const __attribute__((address_space(1))) void*)vp_,                         \
            (__attribute__((address_space(3))) void*)&lV[BUF][cc_ * 8], 16, 0, 0);      \
    }                                                                                   \
} while (0)

#define ATTN_ITER(I, P) do {                                                            \
    __syncthreads();                                                                    \
    { const int mn_ = ((I) + 1) * 64; if (mn_ < 2048) ATTN_STAGE(mn_, 1 - (P)); }       \
    f32x4 st1[4] = {}, st2[4] = {};                                                     \
    _Pragma("unroll")                                                                   \
    for (int c = 0; c < 4; ++c) {                                                       \
        _Pragma("unroll")                                                               \
        for (int ks = 0; ks < 2; ++ks) {                                                \
            bf16x8 kf = *(const bf16x8*)&lK[P][(c * 16 + l16) * 64 +                    \
                                              ((((ks * 4 + quad) ^ l7) & 7) << 3)];     \
            st1[c] = __builtin_amdgcn_mfma_f32_16x16x32_bf16(kf, q1f[ks], st1[c], 0, 0, 0); \
            st2[c] = __builtin_amdgcn_mfma_f32_16x16x32_bf16(kf, q2f[ks], st2[c], 0, 0, 0); \
        } }                                                                             \
    _Pragma("unroll")                                                                   \
    for (int c = 0; c < 4; ++c) {                                                       \
        float p0 = __builtin_amdgcn_exp2f(st1[c][0]);                                   \
        float p1 = __builtin_amdgcn_exp2f(st1[c][1]);                                   \
        float p2 = __builtin_amdgcn_exp2f(st1[c][2]);                                   \
        float p3 = __builtin_amdgcn_exp2f(st1[c][3]);                                   \
        l1 += (p0 + p1) + (p2 + p3);                                                    \
        uint2 w; w.x = pack2(p0, p1); w.y = pack2(p2, p3);                              \
        *(uint2*)&lPw0[l16 * 72 + c * 16 + quad * 4] = w;                               \
        float r0 = __builtin_amdgcn_exp2f(st2[c][0]);                                   \
        float r1 = __builtin_amdgcn_exp2f(st2[c][1]);                                   \
        float r2 = __builtin_amdgcn_exp2f(st2[c][2]);                                   \
        float r3 = __builtin_amdgcn_exp2f(st2[c][3]);                                   \
        l2 += (r0 + r1) + (r2 + r3);                                                    \
        uint2 y; y.x = pack2(r0, r1); y.y = pack2(r2, r3);                              \
        *(uint2*)&lPw1[l16 * 72 + c * 16 + quad * 4] = y;                               \
    }                                                                                   \
    bf16x8 pa1[2], pa2[2];                                                              \
    _Pragma("unroll")                                                                   \
    for (int ks = 0; ks < 2; ++ks) {                                                    \
        pa1[ks] = *(const bf16x8*)&lPw0[l16 * 72 + ks * 32 + quad * 8];                 \
        pa2[ks] = *(const bf16x8*)&lPw1[l16 * 72 + ks * 32 + quad * 8];                 \
    }                                                                                   \
    _Pragma("unroll")                                                                   \
    for (int c = 0; c < 4; ++c) {                                                       \
        _Pragma("unroll")                                                               \
        for (int ks = 0; ks < 2; ++ks) {                                                \
            bf16x8 vf = *(const bf16x8*)&lV[P][(c * 16 + l16) * 64 +                    \
                                              ((((ks * 4 + quad) ^ l7) & 7) << 3)];     \
            o1[c] = __builtin_amdgcn_mfma_f32_16x16x32_bf16(vf, pa1[ks], o1[c], 0, 0, 0); \
            o2[c] = __builtin_amdgcn_mfma_f32_16x16x32_bf16(vf, pa2[ks], o2[c], 0, 0, 0); \
        } }                                                                             \
} while (0)

__global__ __launch_bounds__(256) void attn_fused(
    const ushort_t* __restrict__ Qb, const ushort_t* __restrict__ Q2b,
    const ushort_t* __restrict__ Kb, const ushort_t* __restrict__ Vt,
    ushort_t* __restrict__ Ob)
{
    __shared__ __align__(16) ushort_t lK[2][64 * 64];
    __shared__ __align__(16) ushort_t lV[2][64 * 64];
    __shared__ __align__(16) ushort_t lP[4][2][16 * 72];

    const int qt = blockIdx.x;
    const int bh = blockIdx.y;
    const int tid = threadIdx.x;
    const int wave = tid >> 6, lane = tid & 63;
    const int quad = lane >> 4, l16 = lane & 15;
    const int l7 = l16 & 7;
    const size_t tok0 = (size_t)(bh >> 2) * 2048;
    const int in0 = (bh & 3) * 64;
    const int bh64 = bh * 64;
    ushort_t* lPw0 = &lP[wave][0][0];
    ushort_t* lPw1 = &lP[wave][1][0];

    // Q fragments: direct global load (B-operand layout is row-contiguous 16B)
    bf16x8 q1f[2], q2f[2];
    {
        const ushort_t* qr1 = Qb  + (tok0 + qt * 64 + wave * 16 + l16) * 256 + in0;
        const ushort_t* qr2 = Q2b + (tok0 + qt * 64 + wave * 16 + l16) * 256 + in0;
#pragma unroll
        for (int ks = 0; ks < 2; ++ks) {
            q1f[ks] = *(const bf16x8*)(qr1 + ks * 32 + quad * 8);
            q2f[ks] = *(const bf16x8*)(qr2 + ks * 32 + quad * 8);
        }
    }

    ATTN_STAGE(0, 0);

    f32x4 o1[4] = {}, o2[4] = {};
    float l1 = 0.f, l2 = 0.f;

    for (int i = 0; i < 32; i += 2) {
        ATTN_ITER(i, 0);
        ATTN_ITER(i + 1, 1);
    }

    // l reduction across quads (lanes with same l16)
    l1 += __shfl_xor(l1, 16, 64); l1 += __shfl_xor(l1, 32, 64);
    l2 += __shfl_xor(l2, 16, 64); l2 += __shfl_xor(l2, 32, 64);
    const float inv1 = 0.3f / l1, inv2 = 0.7f / l2;

    // O^T C-layout: row d = c*16 + quad*4 + r, col q = l16 (this wave's 16 q-rows)
    ushort_t* orow = Ob + (tok0 + qt * 64 + wave * 16 + l16) * 256 + in0;
#pragma unroll
    for (int c = 0; c < 4; ++c) {
        const float f0 = o1[c][0] * inv1 + o2[c][0] * inv2;
        const float f1 = o1[c][1] * inv1 + o2[c][1] * inv2;
        const float f2 = o1[c][2] * inv1 + o2[c][2] * inv2;
        const float f3 = o1[c][3] * inv1 + o2[c][3] * inv2;
        uint2 w; w.x = pack2(f0, f1); w.y = pack2(f2, f3);
        *(uint2*)(orow + c * 16 + quad * 4) = w;
    }
}

// ---------------- launch ----------------
extern "C" void kernel_launch(void* const* d_in, const int* in_sizes, int n_in,
                              void* d_out, int out_size, void* d_ws, size_t ws_size,
                              hipStream_t stream)
{
    (void)in_sizes; (void)n_in; (void)out_size; (void)ws_size;
    const float* x1  = (const float*)d_in[0];
    const float* x2  = (const float*)d_in[1];
    const float* ctx = (const float*)d_in[2];
    const float* Wq  = (const float*)d_in[3];
    const float* Wq2 = (const float*)d_in[4];
    const float* Wk  = (const float*)d_in[5];
    const float* Wv  = (const float*)d_in[6];
    const float* Wo  = (const float*)d_in[7];
    const float* bo  = (const float*)d_in[8];
    ushort_t* ws  = (ushort_t*)d_ws;
    float* out = (float*)d_out;

    ushort_t* Wt  = ws + WT_OFF;
    ushort_t* Wot = ws + WOT_OFF;
    ushort_t* QKV = ws + QKV_OFF;
    ushort_t* Q   = QKV;
    ushort_t* Q2  = QKV + 1 * (size_t)QKV_SZ;
    ushort_t* Kp  = QKV + 2 * (size_t)QKV_SZ;
    ushort_t* Vt  = QKV + 3 * (size_t)QKV_SZ;
    ushort_t* Op  = ws + O_OFF;

    transpose_w<<<dim3(512, 5), 256, 0, stream>>>(Wq, Wq2, Wk, Wv, Wo, ws);
    proj_gemm  <<<dim3(128, 4), 256, 0, stream>>>(x1, x2, ctx, Wt, QKV);
    attn_fused <<<dim3(32, 16), 256, 0, stream>>>(Q, Q2, Kp, Vt, Op);
    out_gemm   <<<dim3(128, 2), 256, 0, stream>>>(Op, Wot, bo, out);
}